// Round 9
// baseline (308.428 us; speedup 1.0000x reference)
//
#include <hip/hip_runtime.h>
#include <hip/hip_cooperative_groups.h>
#include <hip/hip_bf16.h>
#include <float.h>

namespace cg = cooperative_groups;

// B=4096, D=512, N=8192, temp=0.5
#define BN_ 4096
#define DD  512
#define NN  8192
#define SCALE 2.0f   // 1/temperature

typedef unsigned short u16;
typedef __attribute__((ext_vector_type(8))) short short8;   // 8 bf16 = 4 VGPRs
typedef __attribute__((ext_vector_type(4))) float floatx4;  // MFMA acc

struct alignas(8) U16x4 { u16 x, y, z, w; };

__device__ __forceinline__ u16 f2bf(float f) {
    union { float f; unsigned u; } c; c.f = f;
    unsigned u = c.u;
    unsigned r = (u + 0x7fffu + ((u >> 16) & 1u)) >> 16;   // RNE
    return (u16)r;
}

__device__ __forceinline__ void async_copy16(const u16* g, u16* l) {
    __builtin_amdgcn_global_load_lds(
        (const __attribute__((address_space(1))) void*)g,
        (__attribute__((address_space(3))) void*)l, 16, 0, 0);
}

// ONE cooperative kernel, three phases split by grid.sync():
//   1) fp32->bf16 convert + per-block positive-dot partial (no atomics)
//   2) symmetric Gram over 2080 lower-triangle 128x128 tiles (exact R3/R7
//      body: 4 waves as 2x2 of 64x64, 16x16x32 bf16 MFMA, XOR-swizzled
//      global_load_lds staging, row+col online-softmax partials)
//   3) per-row logsumexp combine + pos fold + final atomicAdd (blocks 0-31)
// Rationale: measured ~19 us fixed cost PER DISPATCH across R1-R7; fusing
// 3 dispatches -> 1 is worth ~2x the remaining gram headroom.
__global__ __launch_bounds__(256, 3) void fused_kernel(const float* __restrict__ hi,
                                                       const float* __restrict__ hj,
                                                       u16* __restrict__ H,
                                                       float* __restrict__ Mpart,
                                                       float* __restrict__ Spart,
                                                       float* __restrict__ Pos,
                                                       float* __restrict__ out) {
    __shared__ u16 As[128 * 64];    // 16 KB
    __shared__ u16 Bs[128 * 64];    // 16 KB
    __shared__ float Rm[2][128], Rs[2][128];   // row partials / reduce scratch
    __shared__ float Cm[2][128], Cs[2][128];   // col partials

    cg::grid_group grid = cg::this_grid();
    const int tid  = threadIdx.x;
    const int bid  = blockIdx.x;
    const int nB   = gridDim.x;
    const int lane = tid & 63;
    const int wid  = tid >> 6;
    const int quad = lane >> 4;
    const int ln15 = lane & 15;
    const int wr = wid >> 1, wc = wid & 1;
    const int BD = BN_ * DD;

    // ---------------- phase 1: convert + pos partials ----------------
    float dotAcc = 0.0f;
    for (int chunk = bid; chunk < 2048; chunk += nB) {
        int e = (chunk * 256 + tid) * 4;
        float4 a = *(const float4*)(hi + e);
        float4 b = *(const float4*)(hj + e);
        U16x4 oa, ob;
        oa.x = f2bf(a.x); oa.y = f2bf(a.y); oa.z = f2bf(a.z); oa.w = f2bf(a.w);
        ob.x = f2bf(b.x); ob.y = f2bf(b.y); ob.z = f2bf(b.z); ob.w = f2bf(b.w);
        *(U16x4*)(H + e) = oa;
        *(U16x4*)(H + BD + e) = ob;
        dotAcc += a.x * b.x + a.y * b.y + a.z * b.z + a.w * b.w;
    }
#pragma unroll
    for (int msk = 1; msk < 64; msk <<= 1) dotAcc += __shfl_xor(dotAcc, msk);
    {
        float* red = &Rm[0][0];
        if (lane == 0) red[wid] = dotAcc;
        __syncthreads();
        if (tid == 0) {
            Pos[bid] = red[0] + red[1] + red[2] + red[3];
            if (bid == 0) *out = 0.0f;
        }
    }
    __threadfence();
    grid.sync();

    // ---------------- phase 2: Gram tiles (strided over triangle) ----------------
    for (int t = bid; t < 2080; t += nB) {
        int bi = (int)((sqrtf(8.0f * (float)t + 1.0f) - 1.0f) * 0.5f);
        while ((bi + 1) * (bi + 2) / 2 <= t) bi++;
        while (bi * (bi + 1) / 2 > t) bi--;
        const int bj = t - bi * (bi + 1) / 2;
        const bool diag = (bi == bj);
        const int biBase = bi * 128, bjBase = bj * 128;

        const u16* srcA[4];
        int ldsOff[4];
#pragma unroll
        for (int j = 0; j < 4; j++) {
            int c   = j * 256 + tid;        // chunk 0..1023
            int row = c >> 3;               // 0..127
            int kc  = (c & 7) ^ (row & 7);  // swizzle inverse on source side
            srcA[j]   = H + (size_t)(biBase + row) * DD + kc * 8;
            ldsOff[j] = c * 8;
        }
        const ptrdiff_t dB = (ptrdiff_t)(bjBase - biBase) * DD;

        floatx4 acc[4][4];
#pragma unroll
        for (int i = 0; i < 4; i++)
#pragma unroll
            for (int j = 0; j < 4; j++) acc[i][j] = (floatx4)0.0f;

        for (int k0 = 0; k0 < DD; k0 += 64) {
#pragma unroll
            for (int j = 0; j < 4; j++) async_copy16(srcA[j] + k0,      &As[ldsOff[j]]);
#pragma unroll
            for (int j = 0; j < 4; j++) async_copy16(srcA[j] + dB + k0, &Bs[ldsOff[j]]);
            __syncthreads();

#pragma unroll
            for (int kk = 0; kk < 2; kk++) {
                int ck = kk * 4 + quad;     // K-chunk 0..7
                short8 a[4], b[4];
#pragma unroll
                for (int tm = 0; tm < 4; tm++) {
                    int r = wr * 64 + tm * 16 + ln15;
                    a[tm] = *(const short8*)&As[(r * 8 + (ck ^ (r & 7))) * 8];
                }
#pragma unroll
                for (int tn = 0; tn < 4; tn++) {
                    int r = wc * 64 + tn * 16 + ln15;
                    b[tn] = *(const short8*)&Bs[(r * 8 + (ck ^ (r & 7))) * 8];
                }
#pragma unroll
                for (int tm = 0; tm < 4; tm++)
#pragma unroll
                    for (int tn = 0; tn < 4; tn++)
                        acc[tm][tn] = __builtin_amdgcn_mfma_f32_16x16x32_bf16(
                            a[tm], b[tn], acc[tm][tn], 0, 0, 0);
            }
            __syncthreads();
        }

        // scale; mask self-similarity on diagonal tiles
#pragma unroll
        for (int tm = 0; tm < 4; tm++)
#pragma unroll
            for (int tn = 0; tn < 4; tn++)
#pragma unroll
                for (int r = 0; r < 4; r++) {
                    float v = SCALE * acc[tm][tn][r];
                    if (diag) {
                        int lrow = wr * 64 + tm * 16 + quad * 4 + r;
                        int lcol = wc * 64 + tn * 16 + ln15;
                        if (lrow == lcol) v = -FLT_MAX;
                    }
                    acc[tm][tn][r] = v;
                }

        // row pass
#pragma unroll
        for (int tm = 0; tm < 4; tm++) {
#pragma unroll
            for (int r = 0; r < 4; r++) {
                float vmax = -FLT_MAX;
#pragma unroll
                for (int tn = 0; tn < 4; tn++) vmax = fmaxf(vmax, acc[tm][tn][r]);
#pragma unroll
                for (int msk = 1; msk < 16; msk <<= 1)
                    vmax = fmaxf(vmax, __shfl_xor(vmax, msk));
                float s = 0.0f;
#pragma unroll
                for (int tn = 0; tn < 4; tn++) s += __expf(acc[tm][tn][r] - vmax);
#pragma unroll
                for (int msk = 1; msk < 16; msk <<= 1) s += __shfl_xor(s, msk);
                if (ln15 == 0) {
                    int x = wr * 64 + tm * 16 + quad * 4 + r;
                    Rm[wc][x] = vmax; Rs[wc][x] = s;
                }
            }
        }

        // col pass (transpose tile)
        if (!diag) {
#pragma unroll
            for (int tn = 0; tn < 4; tn++) {
                float cm = -FLT_MAX;
#pragma unroll
                for (int tm = 0; tm < 4; tm++)
#pragma unroll
                    for (int r = 0; r < 4; r++) cm = fmaxf(cm, acc[tm][tn][r]);
                cm = fmaxf(cm, __shfl_xor(cm, 16));
                cm = fmaxf(cm, __shfl_xor(cm, 32));
                float s = 0.0f;
#pragma unroll
                for (int tm = 0; tm < 4; tm++)
#pragma unroll
                    for (int r = 0; r < 4; r++) s += __expf(acc[tm][tn][r] - cm);
                s += __shfl_xor(s, 16);
                s += __shfl_xor(s, 32);
                if (quad == 0) {
                    int y = wc * 64 + tn * 16 + ln15;
                    Cm[wr][y] = cm; Cs[wr][y] = s;
                }
            }
        }
        __syncthreads();

        if (tid < 128) {
            float m0 = Rm[0][tid], m1 = Rm[1][tid];
            float s0 = Rs[0][tid], s1 = Rs[1][tid];
            float m = fmaxf(m0, m1);
            float s = s0 * __expf(m0 - m) + s1 * __expf(m1 - m);
            Mpart[(size_t)bj * NN + biBase + tid] = m;
            Spart[(size_t)bj * NN + biBase + tid] = s;
        } else if (!diag) {
            int y = tid - 128;
            float m0 = Cm[0][y], m1 = Cm[1][y];
            float s0 = Cs[0][y], s1 = Cs[1][y];
            float m = fmaxf(m0, m1);
            float s = s0 * __expf(m0 - m) + s1 * __expf(m1 - m);
            Mpart[(size_t)bi * NN + bjBase + y] = m;
            Spart[(size_t)bi * NN + bjBase + y] = s;
        }
        __syncthreads();   // Rm/Cm safe for next tile iteration
    }
    __threadfence();
    grid.sync();

    // ---------------- phase 3: lse combine (blocks 0..31) ----------------
    if (bid < 32) {
        int r = bid * 256 + tid;
        float m = -FLT_MAX, s = 0.0f;
#pragma unroll 8
        for (int c = 0; c < 64; c++) {
            float mc = Mpart[(size_t)c * NN + r];
            float sc = Spart[(size_t)c * NN + r];
            float mn = fmaxf(m, mc);
            s = s * __expf(m - mn) + sc * __expf(mc - mn);
            m = mn;
        }
        float v = m + logf(s);
        if (bid == 0) {   // fold positive-pair partials (nB <= 768)
            float p = 0.0f;
            for (int i = tid; i < nB; i += 256) p += Pos[i];
            v += -4.0f * p;
        }
        float* red = &Rm[0][0];    // 256 contiguous floats (Rm[0..1])
        red[tid] = v;
        __syncthreads();
        for (int st = 128; st > 0; st >>= 1) {
            if (tid < st) red[tid] += red[tid + st];
            __syncthreads();
        }
        if (tid == 0) atomicAdd(out, red[0] * (1.0f / (float)NN));
    }
}

extern "C" void kernel_launch(void* const* d_in, const int* in_sizes, int n_in,
                              void* d_out, int out_size, void* d_ws, size_t ws_size,
                              hipStream_t stream) {
    const float* hi = (const float*)d_in[0];
    const float* hj = (const float*)d_in[1];
    float* out = (float*)d_out;

    u16*   H     = (u16*)d_ws;                                            // 8 MB
    float* Mpart = (float*)((char*)d_ws + (size_t)8 * 1024 * 1024);       // 2 MB
    float* Spart = (float*)((char*)d_ws + (size_t)10 * 1024 * 1024);      // 2 MB
    float* Pos   = (float*)((char*)d_ws + (size_t)12 * 1024 * 1024);      // 3 KB

    // co-residency-safe grid (pure query; deterministic every call)
    int nb = 0;
    hipOccupancyMaxActiveBlocksPerMultiprocessor(&nb, fused_kernel, 256, 0);
    int grid = nb * 256;               // 256 CUs on MI355X
    if (grid > 768) grid = 768;
    if (grid < 256) grid = 256;

    void* args[7] = {(void*)&hi, (void*)&hj, (void*)&H, (void*)&Mpart,
                     (void*)&Spart, (void*)&Pos, (void*)&out};
    hipLaunchCooperativeKernel(fused_kernel, dim3(grid), dim3(256), args, 0, stream);
}

// Round 10
// 285.628 us; speedup vs baseline: 1.0798x; 1.0798x over previous
//
#include <hip/hip_runtime.h>
#include <hip/hip_bf16.h>
#include <float.h>

// B=4096, D=512, N=8192, temp=0.5
#define BN_ 4096
#define DD  512
#define NN  8192
#define SCALE 2.0f   // 1/temperature
#define NTILES 2080  // 64*65/2 lower-triangle 128x128 tiles
#define NLSE   32    // last 32 finishers each reduce 256 rows

typedef unsigned short u16;
typedef __attribute__((ext_vector_type(8))) short short8;   // 8 bf16 = 4 VGPRs
typedef __attribute__((ext_vector_type(4))) float floatx4;  // MFMA acc

struct alignas(8) U16x4 { u16 x, y, z, w; };

__device__ __forceinline__ u16 f2bf(float f) {
    union { float f; unsigned u; } c; c.f = f;
    unsigned u = c.u;
    unsigned r = (u + 0x7fffu + ((u >> 16) & 1u)) >> 16;   // RNE
    return (u16)r;
}

__device__ __forceinline__ void async_copy16(const u16* g, u16* l) {
    __builtin_amdgcn_global_load_lds(
        (const __attribute__((address_space(1))) void*)g,
        (__attribute__((address_space(3))) void*)l, 16, 0, 0);
}

// ------ kernel 1: fp32 -> bf16 concat + per-block positive-dot partial ------
// Also zero-inits d_out and the gram completion counter (harness poisons ws
// with 0xAA before every call). Dispatch-boundary ordering makes both visible
// to the gram dispatch.
__global__ __launch_bounds__(256) void convert_pos_kernel(const float* __restrict__ hi,
                                                          const float* __restrict__ hj,
                                                          u16* __restrict__ H,
                                                          float* __restrict__ Pos,
                                                          unsigned* __restrict__ done,
                                                          float* __restrict__ out) {
    __shared__ float red[4];
    int t = blockIdx.x * 256 + threadIdx.x;     // 2048 blocks -> 524288 threads
    int e = t * 4;
    const int BD = BN_ * DD;
    float4 a = *(const float4*)(hi + e);
    float4 b = *(const float4*)(hj + e);
    U16x4 oa, ob;
    oa.x = f2bf(a.x); oa.y = f2bf(a.y); oa.z = f2bf(a.z); oa.w = f2bf(a.w);
    ob.x = f2bf(b.x); ob.y = f2bf(b.y); ob.z = f2bf(b.z); ob.w = f2bf(b.w);
    *(U16x4*)(H + e) = oa;
    *(U16x4*)(H + BD + e) = ob;
    float dot = a.x * b.x + a.y * b.y + a.z * b.z + a.w * b.w;
#pragma unroll
    for (int msk = 1; msk < 64; msk <<= 1) dot += __shfl_xor(dot, msk);
    int lane = threadIdx.x & 63, wid = threadIdx.x >> 6;
    if (lane == 0) red[wid] = dot;
    __syncthreads();
    if (threadIdx.x == 0) {
        Pos[blockIdx.x] = red[0] + red[1] + red[2] + red[3];
        if (blockIdx.x == 0) { *out = 0.0f; *done = 0u; }
    }
}

// ------------- kernel 2: symmetric Gram + tail-fused lse -------------
// Gram body identical to R3/R7 (62 us, best measured): lower-triangle 128x128
// tiles, 4 waves as 2x2 of 64x64 (16x16x32 bf16 MFMA), XOR-swizzled
// global_load_lds staging, row+col online-softmax partials.
// NEW: no separate lse dispatch. Each block, after its global partial writes,
// does __threadfence() + atomicAdd(done). The last NLSE finishers (old >=
// NTILES-NLSE) spin (acquire, agent scope) until done==NTILES -- entirely
// inside the dispatch tail where those CUs would idle -- then each reduces a
// 256-row lse segment and atomically accumulates into out. Saves one ~19 us
// dispatch. (R9 lesson: cg::grid.sync costs ~100+ us; never use it for this.)
__global__ __launch_bounds__(256, 3) void gram_kernel(const u16* __restrict__ H,
                                                      float* __restrict__ Mpart,
                                                      float* __restrict__ Spart,
                                                      const float* __restrict__ Pos,
                                                      unsigned* __restrict__ done,
                                                      float* __restrict__ out) {
    __shared__ u16 As[128 * 64];    // 16 KB
    __shared__ u16 Bs[128 * 64];    // 16 KB
    __shared__ float Rm[2][128], Rs[2][128];   // row partials per wc
    __shared__ float Cm[2][128], Cs[2][128];   // col partials per wr
    __shared__ unsigned ordShared;

    const int tid  = threadIdx.x;
    const int lane = tid & 63;
    const int wid  = tid >> 6;
    const int quad = lane >> 4;
    const int ln15 = lane & 15;
    const int wr = wid >> 1, wc = wid & 1;

    // lower-triangle decode: blockIdx.x in [0, 2080)
    int t = blockIdx.x;
    int bi = (int)((sqrtf(8.0f * (float)t + 1.0f) - 1.0f) * 0.5f);
    while ((bi + 1) * (bi + 2) / 2 <= t) bi++;
    while (bi * (bi + 1) / 2 > t) bi--;
    const int bj = t - bi * (bi + 1) / 2;
    const bool diag = (bi == bj);
    const int biBase = bi * 128, bjBase = bj * 128;

    // staging pointers, hoisted (B source = A source + uniform delta)
    const u16* srcA[4];
    int ldsOff[4];
#pragma unroll
    for (int j = 0; j < 4; j++) {
        int c   = j * 256 + tid;        // chunk 0..1023
        int row = c >> 3;               // 0..127
        int kc  = (c & 7) ^ (row & 7);  // swizzle inverse on source side
        srcA[j]   = H + (size_t)(biBase + row) * DD + kc * 8;
        ldsOff[j] = c * 8;
    }
    const ptrdiff_t dB = (ptrdiff_t)(bjBase - biBase) * DD;

    floatx4 acc[4][4];
#pragma unroll
    for (int i = 0; i < 4; i++)
#pragma unroll
        for (int j = 0; j < 4; j++) acc[i][j] = (floatx4)0.0f;

    for (int k0 = 0; k0 < DD; k0 += 64) {
#pragma unroll
        for (int j = 0; j < 4; j++) async_copy16(srcA[j] + k0,      &As[ldsOff[j]]);
#pragma unroll
        for (int j = 0; j < 4; j++) async_copy16(srcA[j] + dB + k0, &Bs[ldsOff[j]]);
        __syncthreads();

#pragma unroll
        for (int kk = 0; kk < 2; kk++) {
            int ck = kk * 4 + quad;     // K-chunk 0..7 within the 64-wide tile
            short8 a[4], b[4];
#pragma unroll
            for (int tm = 0; tm < 4; tm++) {
                int r = wr * 64 + tm * 16 + ln15;
                a[tm] = *(const short8*)&As[(r * 8 + (ck ^ (r & 7))) * 8];
            }
#pragma unroll
            for (int tn = 0; tn < 4; tn++) {
                int r = wc * 64 + tn * 16 + ln15;
                b[tn] = *(const short8*)&Bs[(r * 8 + (ck ^ (r & 7))) * 8];
            }
#pragma unroll
            for (int tm = 0; tm < 4; tm++)
#pragma unroll
                for (int tn = 0; tn < 4; tn++)
                    acc[tm][tn] = __builtin_amdgcn_mfma_f32_16x16x32_bf16(
                        a[tm], b[tn], acc[tm][tn], 0, 0, 0);
        }
        __syncthreads();
    }

    // scale in place; mask self-similarity on diagonal tiles
    // C/D layout: local row = tm*16 + quad*4 + reg, local col = tn*16 + ln15
#pragma unroll
    for (int tm = 0; tm < 4; tm++)
#pragma unroll
        for (int tn = 0; tn < 4; tn++)
#pragma unroll
            for (int r = 0; r < 4; r++) {
                float v = SCALE * acc[tm][tn][r];
                if (diag) {
                    int lrow = wr * 64 + tm * 16 + quad * 4 + r;
                    int lcol = wc * 64 + tn * 16 + ln15;
                    if (lrow == lcol) v = -FLT_MAX;
                }
                acc[tm][tn][r] = v;
            }

    // row pass: per-row max+sumexp over this wave's 64 cols
#pragma unroll
    for (int tm = 0; tm < 4; tm++) {
#pragma unroll
        for (int r = 0; r < 4; r++) {
            float vmax = -FLT_MAX;
#pragma unroll
            for (int tn = 0; tn < 4; tn++) vmax = fmaxf(vmax, acc[tm][tn][r]);
#pragma unroll
            for (int msk = 1; msk < 16; msk <<= 1)
                vmax = fmaxf(vmax, __shfl_xor(vmax, msk));
            float s = 0.0f;
#pragma unroll
            for (int tn = 0; tn < 4; tn++) s += __expf(acc[tm][tn][r] - vmax);
#pragma unroll
            for (int msk = 1; msk < 16; msk <<= 1) s += __shfl_xor(s, msk);
            if (ln15 == 0) {
                int x = wr * 64 + tm * 16 + quad * 4 + r;
                Rm[wc][x] = vmax; Rs[wc][x] = s;
            }
        }
    }

    // col pass (transpose tile): per-col max+sumexp over this wave's 64 rows
    if (!diag) {
#pragma unroll
        for (int tn = 0; tn < 4; tn++) {
            float cm = -FLT_MAX;
#pragma unroll
            for (int tm = 0; tm < 4; tm++)
#pragma unroll
                for (int r = 0; r < 4; r++) cm = fmaxf(cm, acc[tm][tn][r]);
            cm = fmaxf(cm, __shfl_xor(cm, 16));
            cm = fmaxf(cm, __shfl_xor(cm, 32));
            float s = 0.0f;
#pragma unroll
            for (int tm = 0; tm < 4; tm++)
#pragma unroll
                for (int r = 0; r < 4; r++) s += __expf(acc[tm][tn][r] - cm);
            s += __shfl_xor(s, 16);
            s += __shfl_xor(s, 32);
            if (quad == 0) {
                int y = wc * 64 + tn * 16 + ln15;
                Cm[wr][y] = cm; Cs[wr][y] = s;
            }
        }
    }
    __syncthreads();

    // merge wave halves, write slot-major partials: Mpart[slot*NN + globalRow]
    if (tid < 128) {
        float m0 = Rm[0][tid], m1 = Rm[1][tid];
        float s0 = Rs[0][tid], s1 = Rs[1][tid];
        float m = fmaxf(m0, m1);
        float s = s0 * __expf(m0 - m) + s1 * __expf(m1 - m);
        Mpart[(size_t)bj * NN + biBase + tid] = m;
        Spart[(size_t)bj * NN + biBase + tid] = s;
    } else if (!diag) {
        int y = tid - 128;
        float m0 = Cm[0][y], m1 = Cm[1][y];
        float s0 = Cs[0][y], s1 = Cs[1][y];
        float m = fmaxf(m0, m1);
        float s = s0 * __expf(m0 - m) + s1 * __expf(m1 - m);
        Mpart[(size_t)bi * NN + bjBase + y] = m;
        Spart[(size_t)bi * NN + bjBase + y] = s;
    }

    // ---- completion accounting: last NLSE finishers run the lse tail ----
    __threadfence();                       // partials visible device-wide
    __syncthreads();                       // all partial-writes of this block issued
    if (tid == 0) ordShared = atomicAdd(done, 1u);   // device scope
    __syncthreads();
    const unsigned ord = ordShared;
    if (ord < NTILES - NLSE) return;
    const int seg = (int)(ord - (NTILES - NLSE));    // 0..31

    // wait until all tiles done (tail-shadow spin, acquire at agent scope)
    if (tid == 0) {
        while (__hip_atomic_load(done, __ATOMIC_ACQUIRE,
                                 __HIP_MEMORY_SCOPE_AGENT) < NTILES) {
            __builtin_amdgcn_s_sleep(8);
        }
    }
    __syncthreads();
    __threadfence();

    // lse over this segment's 256 rows (same slot order as R7's lse_kernel)
    {
        int r = seg * 256 + tid;
        float m = -FLT_MAX, s = 0.0f;
#pragma unroll 8
        for (int c = 0; c < 64; c++) {
            float mc = Mpart[(size_t)c * NN + r];   // coalesced
            float sc = Spart[(size_t)c * NN + r];
            float mn = fmaxf(m, mc);
            s = s * __expf(m - mn) + sc * __expf(mc - mn);
            m = mn;
        }
        float v = m + logf(s);
        if (seg == 0) {   // fold the 2048 positive-dot partials (8 per thread)
            float p = 0.0f;
#pragma unroll
            for (int i = 0; i < 8; i++) p += Pos[tid * 8 + i];
            v += -4.0f * p;
        }
        float* red = &Rm[0][0];    // reuse LDS (256 contiguous floats)
        red[tid] = v;
        __syncthreads();
        for (int st = 128; st > 0; st >>= 1) {
            if (tid < st) red[tid] += red[tid + st];
            __syncthreads();
        }
        if (tid == 0) atomicAdd(out, red[0] * (1.0f / (float)NN));
    }
}

extern "C" void kernel_launch(void* const* d_in, const int* in_sizes, int n_in,
                              void* d_out, int out_size, void* d_ws, size_t ws_size,
                              hipStream_t stream) {
    const float* hi = (const float*)d_in[0];
    const float* hj = (const float*)d_in[1];
    float* out = (float*)d_out;

    u16*      H     = (u16*)d_ws;                                          // 8 MB
    float*    Mpart = (float*)((char*)d_ws + (size_t)8 * 1024 * 1024);     // 2 MB
    float*    Spart = (float*)((char*)d_ws + (size_t)10 * 1024 * 1024);    // 2 MB
    float*    Pos   = (float*)((char*)d_ws + (size_t)12 * 1024 * 1024);    // 8 KB
    unsigned* done  = (unsigned*)((char*)d_ws + (size_t)12 * 1024 * 1024 + 16384);

    convert_pos_kernel<<<2048, 256, 0, stream>>>(hi, hj, H, Pos, done, out);

    gram_kernel<<<NTILES, 256, 0, stream>>>(H, Mpart, Spart, Pos, done, out);
}

// Round 11
// 145.440 us; speedup vs baseline: 2.1207x; 1.9639x over previous
//
#include <hip/hip_runtime.h>
#include <hip/hip_bf16.h>
#include <float.h>

// B=4096, D=512, N=8192, temp=0.5
#define BN_ 4096
#define DD  512
#define NN  8192
#define SCALE 2.0f   // 1/temperature
#define NTILES 2080  // 64*65/2 lower-triangle 128x128 tiles
#define NLSE   32    // last 32 finishers each reduce a 256-row lse segment

typedef unsigned short u16;
typedef __attribute__((ext_vector_type(8))) short short8;   // 8 bf16 = 4 VGPRs
typedef __attribute__((ext_vector_type(4))) float floatx4;  // MFMA acc

struct alignas(8) U16x4 { u16 x, y, z, w; };

__device__ __forceinline__ u16 f2bf(float f) {
    union { float f; unsigned u; } c; c.f = f;
    unsigned u = c.u;
    unsigned r = (u + 0x7fffu + ((u >> 16) & 1u)) >> 16;   // RNE
    return (u16)r;
}

__device__ __forceinline__ void async_copy16(const u16* g, u16* l) {
    __builtin_amdgcn_global_load_lds(
        (const __attribute__((address_space(1))) void*)g,
        (__attribute__((address_space(3))) void*)l, 16, 0, 0);
}

// sc1 (agent-scope, L2-coherent-point) accessors for cross-block data.
// RELAXED on purpose: no acquire/release -> no buffer_inv / buffer_wbl2
// (R10 showed per-block __threadfence = full L2 writeback = 4x slowdown).
__device__ __forceinline__ void st_sc1(float* p, float v) {
    __hip_atomic_store(p, v, __ATOMIC_RELAXED, __HIP_MEMORY_SCOPE_AGENT);
}
__device__ __forceinline__ float ld_sc1(const float* p) {
    return __hip_atomic_load(p, __ATOMIC_RELAXED, __HIP_MEMORY_SCOPE_AGENT);
}

// ------ kernel 1: pure fp32 -> bf16 concat convert + init out/done ------
__global__ __launch_bounds__(256) void convert_kernel(const float* __restrict__ hi,
                                                      const float* __restrict__ hj,
                                                      u16* __restrict__ H,
                                                      unsigned* __restrict__ done,
                                                      float* __restrict__ out) {
    int t = blockIdx.x * 256 + threadIdx.x;     // 2048 blocks -> 524288 threads
    int e = t * 4;
    const int BD = BN_ * DD;
    float4 a = *(const float4*)(hi + e);
    float4 b = *(const float4*)(hj + e);
    U16x4 oa, ob;
    oa.x = f2bf(a.x); oa.y = f2bf(a.y); oa.z = f2bf(a.z); oa.w = f2bf(a.w);
    ob.x = f2bf(b.x); ob.y = f2bf(b.y); ob.z = f2bf(b.z); ob.w = f2bf(b.w);
    *(U16x4*)(H + e) = oa;
    *(U16x4*)(H + BD + e) = ob;
    if (t == 0) { *out = 0.0f; *done = 0u; }   // flushed at kernel end
}

// ------------- kernel 2: symmetric Gram + free pos + tail-fused lse -------------
// Gram body identical to R3/R7 (62 us best). Additions:
//  (a) tiles with bi-bj==32 carry the positive pairs sim[x+B,x] on their local
//      diagonal -> wave-reduce from acc (bf16 precision, unbiased), 1 atomic.
//  (b) partials written/read ONLY via sc1 relaxed atomics (never L2-dirty);
//      completion counted with a relaxed agent fetch_add after __syncthreads
//      (which drains vmcnt(0), i.e. sc1 stores are at the coherent point);
//      the last NLSE finishers spin on relaxed loads (no invalidates) and run
//      the 256-row lse segments in the dispatch tail. Saves one ~19us dispatch.
__global__ __launch_bounds__(256, 3) void gram_kernel(const u16* __restrict__ H,
                                                      float* __restrict__ Mpart,
                                                      float* __restrict__ Spart,
                                                      unsigned* __restrict__ done,
                                                      float* __restrict__ out) {
    __shared__ u16 As[128 * 64];    // 16 KB
    __shared__ u16 Bs[128 * 64];    // 16 KB
    __shared__ float Rm[2][128], Rs[2][128];   // row partials / reduce scratch
    __shared__ float Cm[2][128], Cs[2][128];   // col partials
    __shared__ unsigned ordShared;

    const int tid  = threadIdx.x;
    const int lane = tid & 63;
    const int wid  = tid >> 6;
    const int quad = lane >> 4;
    const int ln15 = lane & 15;
    const int wr = wid >> 1, wc = wid & 1;

    // lower-triangle decode: blockIdx.x in [0, 2080)
    int t = blockIdx.x;
    int bi = (int)((sqrtf(8.0f * (float)t + 1.0f) - 1.0f) * 0.5f);
    while ((bi + 1) * (bi + 2) / 2 <= t) bi++;
    while (bi * (bi + 1) / 2 > t) bi--;
    const int bj = t - bi * (bi + 1) / 2;
    const bool diag = (bi == bj);
    const int biBase = bi * 128, bjBase = bj * 128;

    // staging pointers, hoisted (B source = A source + uniform delta)
    const u16* srcA[4];
    int ldsOff[4];
#pragma unroll
    for (int j = 0; j < 4; j++) {
        int c   = j * 256 + tid;        // chunk 0..1023
        int row = c >> 3;               // 0..127
        int kc  = (c & 7) ^ (row & 7);  // swizzle inverse on source side
        srcA[j]   = H + (size_t)(biBase + row) * DD + kc * 8;
        ldsOff[j] = c * 8;
    }
    const ptrdiff_t dB = (ptrdiff_t)(bjBase - biBase) * DD;

    floatx4 acc[4][4];
#pragma unroll
    for (int i = 0; i < 4; i++)
#pragma unroll
        for (int j = 0; j < 4; j++) acc[i][j] = (floatx4)0.0f;

    for (int k0 = 0; k0 < DD; k0 += 64) {
#pragma unroll
        for (int j = 0; j < 4; j++) async_copy16(srcA[j] + k0,      &As[ldsOff[j]]);
#pragma unroll
        for (int j = 0; j < 4; j++) async_copy16(srcA[j] + dB + k0, &Bs[ldsOff[j]]);
        __syncthreads();

#pragma unroll
        for (int kk = 0; kk < 2; kk++) {
            int ck = kk * 4 + quad;     // K-chunk 0..7 within the 64-wide tile
            short8 a[4], b[4];
#pragma unroll
            for (int tm = 0; tm < 4; tm++) {
                int r = wr * 64 + tm * 16 + ln15;
                a[tm] = *(const short8*)&As[(r * 8 + (ck ^ (r & 7))) * 8];
            }
#pragma unroll
            for (int tn = 0; tn < 4; tn++) {
                int r = wc * 64 + tn * 16 + ln15;
                b[tn] = *(const short8*)&Bs[(r * 8 + (ck ^ (r & 7))) * 8];
            }
#pragma unroll
            for (int tm = 0; tm < 4; tm++)
#pragma unroll
                for (int tn = 0; tn < 4; tn++)
                    acc[tm][tn] = __builtin_amdgcn_mfma_f32_16x16x32_bf16(
                        a[tm], b[tn], acc[tm][tn], 0, 0, 0);
        }
        __syncthreads();
    }

    // scale in place; mask self-similarity on diagonal tiles
    // C/D layout: local row = tm*16 + quad*4 + reg, local col = tn*16 + ln15
#pragma unroll
    for (int tm = 0; tm < 4; tm++)
#pragma unroll
        for (int tn = 0; tn < 4; tn++)
#pragma unroll
            for (int r = 0; r < 4; r++) {
                float v = SCALE * acc[tm][tn][r];
                if (diag) {
                    int lrow = wr * 64 + tm * 16 + quad * 4 + r;
                    int lcol = wc * 64 + tn * 16 + ln15;
                    if (lrow == lcol) v = -FLT_MAX;
                }
                acc[tm][tn][r] = v;
            }

    // positive pairs: tiles with bi-bj==32 hold sim[x+B, x] on the local
    // diagonal. Sum_N pos = 2 * sum over these 32 tile-diagonals.
    if (bi - bj == 32) {
        float d = 0.0f;
        if (wr == wc) {
#pragma unroll
            for (int tm = 0; tm < 4; tm++)
#pragma unroll
                for (int r = 0; r < 4; r++)
                    if (ln15 == quad * 4 + r) d += acc[tm][tm][r];
        }
#pragma unroll
        for (int msk = 1; msk < 64; msk <<= 1) d += __shfl_xor(d, msk);
        if (lane == 0 && (wr == wc)) atomicAdd(out, d * (-2.0f / (float)NN));
    }

    // row pass: per-row max+sumexp over this wave's 64 cols
#pragma unroll
    for (int tm = 0; tm < 4; tm++) {
#pragma unroll
        for (int r = 0; r < 4; r++) {
            float vmax = -FLT_MAX;
#pragma unroll
            for (int tn = 0; tn < 4; tn++) vmax = fmaxf(vmax, acc[tm][tn][r]);
#pragma unroll
            for (int msk = 1; msk < 16; msk <<= 1)
                vmax = fmaxf(vmax, __shfl_xor(vmax, msk));
            float s = 0.0f;
#pragma unroll
            for (int tn = 0; tn < 4; tn++) s += __expf(acc[tm][tn][r] - vmax);
#pragma unroll
            for (int msk = 1; msk < 16; msk <<= 1) s += __shfl_xor(s, msk);
            if (ln15 == 0) {
                int x = wr * 64 + tm * 16 + quad * 4 + r;
                Rm[wc][x] = vmax; Rs[wc][x] = s;
            }
        }
    }

    // col pass (transpose tile): per-col max+sumexp over this wave's 64 rows
    if (!diag) {
#pragma unroll
        for (int tn = 0; tn < 4; tn++) {
            float cm = -FLT_MAX;
#pragma unroll
            for (int tm = 0; tm < 4; tm++)
#pragma unroll
                for (int r = 0; r < 4; r++) cm = fmaxf(cm, acc[tm][tn][r]);
            cm = fmaxf(cm, __shfl_xor(cm, 16));
            cm = fmaxf(cm, __shfl_xor(cm, 32));
            float s = 0.0f;
#pragma unroll
            for (int tm = 0; tm < 4; tm++)
#pragma unroll
                for (int r = 0; r < 4; r++) s += __expf(acc[tm][tn][r] - cm);
            s += __shfl_xor(s, 16);
            s += __shfl_xor(s, 32);
            if (quad == 0) {
                int y = wc * 64 + tn * 16 + ln15;
                Cm[wr][y] = cm; Cs[wr][y] = s;
            }
        }
    }
    __syncthreads();

    // merge wave halves, write slot-major partials via sc1 stores
    if (tid < 128) {
        float m0 = Rm[0][tid], m1 = Rm[1][tid];
        float s0 = Rs[0][tid], s1 = Rs[1][tid];
        float m = fmaxf(m0, m1);
        float s = s0 * __expf(m0 - m) + s1 * __expf(m1 - m);
        st_sc1(&Mpart[(size_t)bj * NN + biBase + tid], m);
        st_sc1(&Spart[(size_t)bj * NN + biBase + tid], s);
    } else if (!diag) {
        int y = tid - 128;
        float m0 = Cm[0][y], m1 = Cm[1][y];
        float s0 = Cs[0][y], s1 = Cs[1][y];
        float m = fmaxf(m0, m1);
        float s = s0 * __expf(m0 - m) + s1 * __expf(m1 - m);
        st_sc1(&Mpart[(size_t)bi * NN + bjBase + y], m);
        st_sc1(&Spart[(size_t)bi * NN + bjBase + y], s);
    }

    // ---- completion: __syncthreads drains vmcnt(0) -> sc1 stores are at the
    // coherent point; then ONE relaxed agent fetch_add. No fences anywhere.
    __syncthreads();
    if (tid == 0)
        ordShared = __hip_atomic_fetch_add(done, 1u, __ATOMIC_RELAXED,
                                           __HIP_MEMORY_SCOPE_AGENT);
    __syncthreads();
    const unsigned ord = ordShared;
    if (ord < NTILES - NLSE) return;
    const int seg = (int)(ord - (NTILES - NLSE));    // 0..31

    // tail-shadow spin: relaxed agent loads (sc1, no L2 invalidates)
    if (tid == 0) {
        while (__hip_atomic_load(done, __ATOMIC_RELAXED,
                                 __HIP_MEMORY_SCOPE_AGENT) < NTILES) {
            __builtin_amdgcn_s_sleep(2);
        }
    }
    __syncthreads();

    // lse over this segment's 256 rows; partials read via sc1 loads
    {
        int r = seg * 256 + tid;
        float m = -FLT_MAX, s = 0.0f;
#pragma unroll 4
        for (int c = 0; c < 64; c++) {
            float mc = ld_sc1(&Mpart[(size_t)c * NN + r]);
            float sc = ld_sc1(&Spart[(size_t)c * NN + r]);
            float mn = fmaxf(m, mc);
            s = s * __expf(m - mn) + sc * __expf(mc - mn);
            m = mn;
        }
        float v = m + logf(s);
        float* red = &Rm[0][0];    // reuse LDS (256 contiguous floats)
        red[tid] = v;
        __syncthreads();
        for (int st = 128; st > 0; st >>= 1) {
            if (tid < st) red[tid] += red[tid + st];
            __syncthreads();
        }
        if (tid == 0) atomicAdd(out, red[0] * (1.0f / (float)NN));
    }
}

extern "C" void kernel_launch(void* const* d_in, const int* in_sizes, int n_in,
                              void* d_out, int out_size, void* d_ws, size_t ws_size,
                              hipStream_t stream) {
    const float* hi = (const float*)d_in[0];
    const float* hj = (const float*)d_in[1];
    float* out = (float*)d_out;

    u16*      H     = (u16*)d_ws;                                          // 8 MB
    float*    Mpart = (float*)((char*)d_ws + (size_t)8 * 1024 * 1024);     // 2 MB
    float*    Spart = (float*)((char*)d_ws + (size_t)10 * 1024 * 1024);    // 2 MB
    unsigned* done  = (unsigned*)((char*)d_ws + (size_t)12 * 1024 * 1024);

    convert_kernel<<<2048, 256, 0, stream>>>(hi, hj, H, done, out);

    gram_kernel<<<NTILES, 256, 0, stream>>>(H, Mpart, Spart, done, out);
}

// Round 12
// 141.136 us; speedup vs baseline: 2.1853x; 1.0305x over previous
//
#include <hip/hip_runtime.h>
#include <hip/hip_bf16.h>
#include <float.h>

// B=4096, D=512, N=8192, temp=0.5
#define BN_ 4096
#define DD  512
#define NN  8192
#define SCALE 2.0f   // 1/temperature
#define NTILES 2080  // 64*65/2 lower-triangle 128x128 tiles
#define NLSE   32    // last 32 finishers each reduce a 256-row lse segment

typedef unsigned short u16;
typedef __attribute__((ext_vector_type(8))) short short8;   // 8 bf16 = 4 VGPRs
typedef __attribute__((ext_vector_type(4))) float floatx4;  // MFMA acc

struct alignas(8) U16x4 { u16 x, y, z, w; };

__device__ __forceinline__ u16 f2bf(float f) {
    union { float f; unsigned u; } c; c.f = f;
    unsigned u = c.u;
    unsigned r = (u + 0x7fffu + ((u >> 16) & 1u)) >> 16;   // RNE
    return (u16)r;
}

__device__ __forceinline__ void async_copy16(const u16* g, u16* l) {
    __builtin_amdgcn_global_load_lds(
        (const __attribute__((address_space(1))) void*)g,
        (__attribute__((address_space(3))) void*)l, 16, 0, 0);
}

// sc1 (agent-scope) store for cross-block partials. RELAXED: no acquire/
// release -> no buffer_inv/buffer_wbl2 (R10: per-block __threadfence = full
// L2 writeback = 4x slowdown). Readers may use PLAIN loads: these lines are
// touched only by sc1 stores (no L2 allocation) before the tail, so no XCD
// L2 can hold a stale copy (R11: atomic sc1 LOADS serialized ~24us; plain
// loads pipeline and cost ~3us for the same traffic).
__device__ __forceinline__ void st_sc1(float* p, float v) {
    __hip_atomic_store(p, v, __ATOMIC_RELAXED, __HIP_MEMORY_SCOPE_AGENT);
}

// ------ kernel 1: pure fp32 -> bf16 concat convert + init out/done ------
__global__ __launch_bounds__(256) void convert_kernel(const float* __restrict__ hi,
                                                      const float* __restrict__ hj,
                                                      u16* __restrict__ H,
                                                      unsigned* __restrict__ done,
                                                      float* __restrict__ out) {
    int t = blockIdx.x * 256 + threadIdx.x;     // 2048 blocks -> 524288 threads
    int e = t * 4;
    const int BD = BN_ * DD;
    float4 a = *(const float4*)(hi + e);
    float4 b = *(const float4*)(hj + e);
    U16x4 oa, ob;
    oa.x = f2bf(a.x); oa.y = f2bf(a.y); oa.z = f2bf(a.z); oa.w = f2bf(a.w);
    ob.x = f2bf(b.x); ob.y = f2bf(b.y); ob.z = f2bf(b.z); ob.w = f2bf(b.w);
    *(U16x4*)(H + e) = oa;
    *(U16x4*)(H + BD + e) = ob;
    if (t == 0) { *out = 0.0f; *done = 0u; }   // flushed at dispatch end
}

// ------------- kernel 2: symmetric Gram + free pos + tail-fused lse -------------
// Gram body identical to R3/R7 (62 us best). pos comes free from tiles with
// bi-bj==32 (local diagonal = sim[x+B,x]). Partials written via sc1 stores;
// completion via one relaxed agent fetch_add per block after __syncthreads
// (drains vmcnt -> stores at coherent point). Last NLSE finishers spin on
// relaxed loads, then run the lse segments with PLAIN pipelined loads.
__global__ __launch_bounds__(256, 3) void gram_kernel(const u16* __restrict__ H,
                                                      float* __restrict__ Mpart,
                                                      float* __restrict__ Spart,
                                                      unsigned* __restrict__ done,
                                                      float* __restrict__ out) {
    __shared__ u16 As[128 * 64];    // 16 KB
    __shared__ u16 Bs[128 * 64];    // 16 KB
    __shared__ float Rm[2][128], Rs[2][128];   // row partials / reduce scratch
    __shared__ float Cm[2][128], Cs[2][128];   // col partials
    __shared__ unsigned ordShared;

    const int tid  = threadIdx.x;
    const int lane = tid & 63;
    const int wid  = tid >> 6;
    const int quad = lane >> 4;
    const int ln15 = lane & 15;
    const int wr = wid >> 1, wc = wid & 1;

    // lower-triangle decode: blockIdx.x in [0, 2080)
    int t = blockIdx.x;
    int bi = (int)((sqrtf(8.0f * (float)t + 1.0f) - 1.0f) * 0.5f);
    while ((bi + 1) * (bi + 2) / 2 <= t) bi++;
    while (bi * (bi + 1) / 2 > t) bi--;
    const int bj = t - bi * (bi + 1) / 2;
    const bool diag = (bi == bj);
    const int biBase = bi * 128, bjBase = bj * 128;

    // staging pointers, hoisted (B source = A source + uniform delta)
    const u16* srcA[4];
    int ldsOff[4];
#pragma unroll
    for (int j = 0; j < 4; j++) {
        int c   = j * 256 + tid;        // chunk 0..1023
        int row = c >> 3;               // 0..127
        int kc  = (c & 7) ^ (row & 7);  // swizzle inverse on source side
        srcA[j]   = H + (size_t)(biBase + row) * DD + kc * 8;
        ldsOff[j] = c * 8;
    }
    const ptrdiff_t dB = (ptrdiff_t)(bjBase - biBase) * DD;

    floatx4 acc[4][4];
#pragma unroll
    for (int i = 0; i < 4; i++)
#pragma unroll
        for (int j = 0; j < 4; j++) acc[i][j] = (floatx4)0.0f;

    for (int k0 = 0; k0 < DD; k0 += 64) {
#pragma unroll
        for (int j = 0; j < 4; j++) async_copy16(srcA[j] + k0,      &As[ldsOff[j]]);
#pragma unroll
        for (int j = 0; j < 4; j++) async_copy16(srcA[j] + dB + k0, &Bs[ldsOff[j]]);
        __syncthreads();

#pragma unroll
        for (int kk = 0; kk < 2; kk++) {
            int ck = kk * 4 + quad;     // K-chunk 0..7 within the 64-wide tile
            short8 a[4], b[4];
#pragma unroll
            for (int tm = 0; tm < 4; tm++) {
                int r = wr * 64 + tm * 16 + ln15;
                a[tm] = *(const short8*)&As[(r * 8 + (ck ^ (r & 7))) * 8];
            }
#pragma unroll
            for (int tn = 0; tn < 4; tn++) {
                int r = wc * 64 + tn * 16 + ln15;
                b[tn] = *(const short8*)&Bs[(r * 8 + (ck ^ (r & 7))) * 8];
            }
#pragma unroll
            for (int tm = 0; tm < 4; tm++)
#pragma unroll
                for (int tn = 0; tn < 4; tn++)
                    acc[tm][tn] = __builtin_amdgcn_mfma_f32_16x16x32_bf16(
                        a[tm], b[tn], acc[tm][tn], 0, 0, 0);
        }
        __syncthreads();
    }

    // scale in place; mask self-similarity on diagonal tiles
    // C/D layout: local row = tm*16 + quad*4 + reg, local col = tn*16 + ln15
#pragma unroll
    for (int tm = 0; tm < 4; tm++)
#pragma unroll
        for (int tn = 0; tn < 4; tn++)
#pragma unroll
            for (int r = 0; r < 4; r++) {
                float v = SCALE * acc[tm][tn][r];
                if (diag) {
                    int lrow = wr * 64 + tm * 16 + quad * 4 + r;
                    int lcol = wc * 64 + tn * 16 + ln15;
                    if (lrow == lcol) v = -FLT_MAX;
                }
                acc[tm][tn][r] = v;
            }

    // positive pairs: tiles with bi-bj==32 hold sim[x+B, x] on the local
    // diagonal. Sum_N pos = 2 * sum over these 32 tile-diagonals.
    if (bi - bj == 32) {
        float d = 0.0f;
        if (wr == wc) {
#pragma unroll
            for (int tm = 0; tm < 4; tm++)
#pragma unroll
                for (int r = 0; r < 4; r++)
                    if (ln15 == quad * 4 + r) d += acc[tm][tm][r];
        }
#pragma unroll
        for (int msk = 1; msk < 64; msk <<= 1) d += __shfl_xor(d, msk);
        if (lane == 0 && (wr == wc)) atomicAdd(out, d * (-2.0f / (float)NN));
    }

    // row pass: per-row max+sumexp over this wave's 64 cols
#pragma unroll
    for (int tm = 0; tm < 4; tm++) {
#pragma unroll
        for (int r = 0; r < 4; r++) {
            float vmax = -FLT_MAX;
#pragma unroll
            for (int tn = 0; tn < 4; tn++) vmax = fmaxf(vmax, acc[tm][tn][r]);
#pragma unroll
            for (int msk = 1; msk < 16; msk <<= 1)
                vmax = fmaxf(vmax, __shfl_xor(vmax, msk));
            float s = 0.0f;
#pragma unroll
            for (int tn = 0; tn < 4; tn++) s += __expf(acc[tm][tn][r] - vmax);
#pragma unroll
            for (int msk = 1; msk < 16; msk <<= 1) s += __shfl_xor(s, msk);
            if (ln15 == 0) {
                int x = wr * 64 + tm * 16 + quad * 4 + r;
                Rm[wc][x] = vmax; Rs[wc][x] = s;
            }
        }
    }

    // col pass (transpose tile): per-col max+sumexp over this wave's 64 rows
    if (!diag) {
#pragma unroll
        for (int tn = 0; tn < 4; tn++) {
            float cm = -FLT_MAX;
#pragma unroll
            for (int tm = 0; tm < 4; tm++)
#pragma unroll
                for (int r = 0; r < 4; r++) cm = fmaxf(cm, acc[tm][tn][r]);
            cm = fmaxf(cm, __shfl_xor(cm, 16));
            cm = fmaxf(cm, __shfl_xor(cm, 32));
            float s = 0.0f;
#pragma unroll
            for (int tm = 0; tm < 4; tm++)
#pragma unroll
                for (int r = 0; r < 4; r++) s += __expf(acc[tm][tn][r] - cm);
            s += __shfl_xor(s, 16);
            s += __shfl_xor(s, 32);
            if (quad == 0) {
                int y = wc * 64 + tn * 16 + ln15;
                Cm[wr][y] = cm; Cs[wr][y] = s;
            }
        }
    }
    __syncthreads();

    // merge wave halves, write slot-major partials via sc1 stores
    if (tid < 128) {
        float m0 = Rm[0][tid], m1 = Rm[1][tid];
        float s0 = Rs[0][tid], s1 = Rs[1][tid];
        float m = fmaxf(m0, m1);
        float s = s0 * __expf(m0 - m) + s1 * __expf(m1 - m);
        st_sc1(&Mpart[(size_t)bj * NN + biBase + tid], m);
        st_sc1(&Spart[(size_t)bj * NN + biBase + tid], s);
    } else if (!diag) {
        int y = tid - 128;
        float m0 = Cm[0][y], m1 = Cm[1][y];
        float s0 = Cs[0][y], s1 = Cs[1][y];
        float m = fmaxf(m0, m1);
        float s = s0 * __expf(m0 - m) + s1 * __expf(m1 - m);
        st_sc1(&Mpart[(size_t)bi * NN + bjBase + y], m);
        st_sc1(&Spart[(size_t)bi * NN + bjBase + y], s);
    }

    // ---- completion: __syncthreads drains vmcnt(0) -> sc1 stores are at the
    // coherent point; then ONE relaxed agent fetch_add. No fences anywhere.
    __syncthreads();
    if (tid == 0)
        ordShared = __hip_atomic_fetch_add(done, 1u, __ATOMIC_RELAXED,
                                           __HIP_MEMORY_SCOPE_AGENT);
    __syncthreads();
    const unsigned ord = ordShared;
    if (ord < NTILES - NLSE) return;
    const int seg = (int)(ord - (NTILES - NLSE));    // 0..31

    // tail-shadow spin: relaxed agent loads (no invalidates)
    if (tid == 0) {
        while (__hip_atomic_load(done, __ATOMIC_RELAXED,
                                 __HIP_MEMORY_SCOPE_AGENT) < NTILES) {
            __builtin_amdgcn_s_sleep(2);
        }
    }
    __syncthreads();   // compiler+exec barrier: loads below issue after spin

    // lse over this segment's 256 rows -- PLAIN loads (pipelined; safe: these
    // lines exist only at the coherent point, no L2 can hold a stale copy)
    {
        int r = seg * 256 + tid;
        float m = -FLT_MAX, s = 0.0f;
#pragma unroll 8
        for (int c = 0; c < 64; c++) {
            float mc = Mpart[(size_t)c * NN + r];   // coalesced
            float sc = Spart[(size_t)c * NN + r];
            float mn = fmaxf(m, mc);
            s = s * __expf(m - mn) + sc * __expf(mc - mn);
            m = mn;
        }
        float v = m + logf(s);
        float* red = &Rm[0][0];    // reuse LDS (256 contiguous floats)
        red[tid] = v;
        __syncthreads();
        for (int st = 128; st > 0; st >>= 1) {
            if (tid < st) red[tid] += red[tid + st];
            __syncthreads();
        }
        if (tid == 0) atomicAdd(out, red[0] * (1.0f / (float)NN));
    }
}

extern "C" void kernel_launch(void* const* d_in, const int* in_sizes, int n_in,
                              void* d_out, int out_size, void* d_ws, size_t ws_size,
                              hipStream_t stream) {
    const float* hi = (const float*)d_in[0];
    const float* hj = (const float*)d_in[1];
    float* out = (float*)d_out;

    u16*      H     = (u16*)d_ws;                                          // 8 MB
    float*    Mpart = (float*)((char*)d_ws + (size_t)8 * 1024 * 1024);     // 2 MB
    float*    Spart = (float*)((char*)d_ws + (size_t)10 * 1024 * 1024);    // 2 MB
    unsigned* done  = (unsigned*)((char*)d_ws + (size_t)12 * 1024 * 1024);

    convert_kernel<<<2048, 256, 0, stream>>>(hi, hj, H, done, out);

    gram_kernel<<<NTILES, 256, 0, stream>>>(H, Mpart, Spart, done, out);
}